// Round 2
// baseline (197.838 us; speedup 1.0000x reference)
//
#include <hip/hip_runtime.h>
#include <stdint.h>
#include <stddef.h>

// ---------------- types ----------------
typedef __attribute__((ext_vector_type(8))) short bf16x8;          // MFMA A/B frag (8 bf16)
typedef __attribute__((ext_vector_type(8))) unsigned short u16x8;  // 16B LDS store
typedef __attribute__((ext_vector_type(4))) float f32x4;           // MFMA C/D frag

typedef const __attribute__((address_space(1))) void* gptr1_t;
typedef __attribute__((address_space(3))) void* lptr3_t;

#define GLOAD_LDS16(gp, lp) \
  __builtin_amdgcn_global_load_lds((gptr1_t)(gp), (lptr3_t)(lp), 16, 0, 0)

__device__ __forceinline__ uint16_t f2bf(float f) {
  uint32_t u = __builtin_bit_cast(uint32_t, f);
  u += 0x7fffu + ((u >> 16) & 1u);   // RNE
  return (uint16_t)(u >> 16);
}

// ---------------- problem constants ----------------
#define MB   16384      // batch
#define NP   256        // W*H positions
#define KDIM 1024       // NP*EMB
#define NDIM 1024       // OUT

// ---------------- kernel 1: Webf[c][e] = bf16(W_embed[c][e] + b_embed[e]) ----------------
// 1024 x 4 table, 8 KB — stays L1-hot in the GEMM.
__global__ void build_webf_kernel(const float* __restrict__ We,
                                  const float* __restrict__ be,
                                  uint16_t* __restrict__ Webf) {
  const int t = blockIdx.x * 256 + threadIdx.x;   // 4096 total
  Webf[t] = f2bf(We[t] + be[t & 3]);
}

// ---------------- kernel 2: Bt[n][k] = bf16(W_dense[k][n]) ----------------
__global__ void build_bt_kernel(const float* __restrict__ Wd,
                                uint16_t* __restrict__ Bt) {
  __shared__ uint16_t tile[32][33];               // +1 pad: no bank conflicts
  const int k0 = blockIdx.y * 32;
  const int n0 = blockIdx.x * 32;
  const int tx = threadIdx.x;                     // 0..31
  const int ty = threadIdx.y;                     // 0..7
  #pragma unroll
  for (int r = 0; r < 32; r += 8)
    tile[ty + r][tx] = f2bf(Wd[(size_t)(k0 + ty + r) * NDIM + n0 + tx]);
  __syncthreads();
  #pragma unroll
  for (int r = 0; r < 32; r += 8)
    Bt[(size_t)(n0 + ty + r) * KDIM + k0 + tx] = tile[tx][ty + r];
}

// ---------------- kernel 3: fused gather + bf16 GEMM ----------------
// C[b][n] = sum_k A[b][k] * Bt[n][k] + bias[n],  A[b][p*4+e] = Webf[x[b][p]][e]
#define BM 128
#define BN 128
#define BK 32              // 8 positions per K-step
#define NK (KDIM / BK)     // 32 K-steps

__global__ __launch_bounds__(256) void gemm_fused_kernel(
    const int* __restrict__ x,
    const uint16_t* __restrict__ Webf,
    const uint16_t* __restrict__ Bt,
    const float* __restrict__ bias,
    float* __restrict__ C) {
  __shared__ uint16_t As[BM * BK];   // 8 KB, row-major 128x32
  __shared__ uint16_t Bs[BN * BK];   // 8 KB

  const int tid  = threadIdx.x;
  const int bm   = blockIdx.x;       // 128 m-tiles
  const int bn   = blockIdx.y;       // 8 n-tiles
  const int wave = tid >> 6;
  const int lane = tid & 63;
  const int wr   = wave >> 1;        // 2x2 wave grid, 64x64 per wave
  const int wc   = wave & 1;
  const int lm   = lane & 15;
  const int q    = lane >> 4;

  const int row0 = bm * BM;
  const int col0 = bn * BN;

  // B staging (global_load_lds, lane-contiguous)
  const int srow = tid >> 2;          // 0..63
  const int scol = (tid & 3) * 8;     // 8 bf16 = 16B

  // A staging: thread covers As row (arow | arow+64), k = adp*8..+8 (2 positions)
  const int arow = tid >> 2;          // 0..63
  const int adp  = tid & 3;           // position-pair index within K-step
  const int* xr0 = x + (size_t)(row0 + arow)      * NP + adp * 2;
  const int* xr1 = x + (size_t)(row0 + 64 + arow) * NP + adp * 2;
  const ushort4* WB = (const ushort4*)Webf;       // 8B per class row

  f32x4 acc[4][4];
  #pragma unroll
  for (int i = 0; i < 4; i++)
    #pragma unroll
    for (int j = 0; j < 4; j++)
      acc[i][j] = (f32x4){0.f, 0.f, 0.f, 0.f};

  // pipeline depth 1: gather for kt=0 before the loop
  int2 i0 = *(const int2*)(xr0);
  int2 i1 = *(const int2*)(xr1);
  ushort4 g0 = WB[i0.x], g1 = WB[i0.y];
  ushort4 g2 = WB[i1.x], g3 = WB[i1.y];

  for (int kt = 0; kt < NK; ++kt) {
    const int k0 = kt * BK;

    // B-tile: async global->LDS
    GLOAD_LDS16(Bt + (size_t)(col0      + srow) * KDIM + k0 + scol, Bs + tid * 8);
    GLOAD_LDS16(Bt + (size_t)(col0 + 64 + srow) * KDIM + k0 + scol, Bs + 2048 + tid * 8);

    // A-tile: write this step's gathered values, lane-contiguous b128
    u16x8 v0 = { g0.x, g0.y, g0.z, g0.w, g1.x, g1.y, g1.z, g1.w };
    u16x8 v1 = { g2.x, g2.y, g2.z, g2.w, g3.x, g3.y, g3.z, g3.w };
    *(u16x8*)(As + tid * 8)        = v0;
    *(u16x8*)(As + 2048 + tid * 8) = v1;

    // prefetch next step's gathers (overlaps MFMA below)
    if (kt + 1 < NK) {
      int2 j0 = *(const int2*)(xr0 + (kt + 1) * 8);
      int2 j1 = *(const int2*)(xr1 + (kt + 1) * 8);
      g0 = WB[j0.x]; g1 = WB[j0.y];
      g2 = WB[j1.x]; g3 = WB[j1.y];
    }

    __syncthreads();

    bf16x8 af[4], bfr[4];
    #pragma unroll
    for (int i = 0; i < 4; i++)
      af[i] = *(const bf16x8*)(As + (wr * 64 + i * 16 + lm) * BK + q * 8);
    #pragma unroll
    for (int j = 0; j < 4; j++)
      bfr[j] = *(const bf16x8*)(Bs + (wc * 64 + j * 16 + lm) * BK + q * 8);

    #pragma unroll
    for (int i = 0; i < 4; i++)
      #pragma unroll
      for (int j = 0; j < 4; j++)
        acc[i][j] = __builtin_amdgcn_mfma_f32_16x16x32_bf16(af[i], bfr[j], acc[i][j], 0, 0, 0);

    __syncthreads();
  }

  // epilogue: D[row = q*4 + r][col = lm] per 16x16 frag (m89/m91-verified)
  float bvals[4];
  #pragma unroll
  for (int j = 0; j < 4; j++)
    bvals[j] = bias[col0 + wc * 64 + j * 16 + lm];

  #pragma unroll
  for (int i = 0; i < 4; i++) {
    const int rbase = row0 + wr * 64 + i * 16 + q * 4;
    #pragma unroll
    for (int j = 0; j < 4; j++) {
      const int col = col0 + wc * 64 + j * 16 + lm;
      #pragma unroll
      for (int r = 0; r < 4; r++)
        C[(size_t)(rbase + r) * NDIM + col] = acc[i][j][r] + bvals[j];
    }
  }
}

// ---------------- fallback (workspace too small): fp32 naive ----------------
__global__ void naive_kernel(const int* __restrict__ x,
                             const float* __restrict__ We,
                             const float* __restrict__ be,
                             const float* __restrict__ Wd,
                             const float* __restrict__ bd,
                             float* __restrict__ out) {
  __shared__ float emb[KDIM];
  const int b = blockIdx.x;
  const int tid = threadIdx.x;
  {
    const int cls = x[(size_t)b * NP + tid];
    const float4 e  = *(const float4*)(We + (size_t)cls * 4);
    const float4 bb = *(const float4*)be;
    emb[tid * 4 + 0] = e.x + bb.x;
    emb[tid * 4 + 1] = e.y + bb.y;
    emb[tid * 4 + 2] = e.z + bb.z;
    emb[tid * 4 + 3] = e.w + bb.w;
  }
  __syncthreads();
  float acc0 = bd[tid], acc1 = bd[tid + 256], acc2 = bd[tid + 512], acc3 = bd[tid + 768];
  for (int k = 0; k < KDIM; ++k) {
    const float a = emb[k];
    const float* w = Wd + (size_t)k * NDIM + tid;
    acc0 += a * w[0];
    acc1 += a * w[256];
    acc2 += a * w[512];
    acc3 += a * w[768];
  }
  float* o = out + (size_t)b * NDIM + tid;
  o[0] = acc0; o[256] = acc1; o[512] = acc2; o[768] = acc3;
}

// ---------------- launch ----------------
extern "C" void kernel_launch(void* const* d_in, const int* in_sizes, int n_in,
                              void* d_out, int out_size, void* d_ws, size_t ws_size,
                              hipStream_t stream) {
  const int*   x  = (const int*)d_in[0];
  const float* We = (const float*)d_in[1];
  const float* be = (const float*)d_in[2];
  const float* Wd = (const float*)d_in[3];
  const float* bd = (const float*)d_in[4];
  float* out = (float*)d_out;

  const size_t needW = (size_t)KDIM * 4 * sizeof(uint16_t);     // Webf: 8 KB (1024*4)
  const size_t needB = (size_t)NDIM * KDIM * sizeof(uint16_t);  // Bt: 2 MB

  if (ws_size >= needW + needB) {
    uint16_t* Webf = (uint16_t*)d_ws;
    uint16_t* Btw  = (uint16_t*)((char*)d_ws + needW);
    build_webf_kernel<<<16, 256, 0, stream>>>(We, be, Webf);
    build_bt_kernel<<<dim3(NDIM / 32, KDIM / 32), dim3(32, 8), 0, stream>>>(Wd, Btw);
    gemm_fused_kernel<<<dim3(MB / BM, NDIM / BN), 256, 0, stream>>>(x, Webf, Btw, bd, out);
  } else {
    naive_kernel<<<MB, 256, 0, stream>>>(x, We, be, Wd, bd, out);
  }
}

// Round 3
// 133.781 us; speedup vs baseline: 1.4788x; 1.4788x over previous
//
#include <hip/hip_runtime.h>
#include <stdint.h>
#include <stddef.h>

// ---------------- types ----------------
typedef __attribute__((ext_vector_type(8))) short bf16x8;          // MFMA A/B frag (8 bf16)
typedef __attribute__((ext_vector_type(8))) unsigned short u16x8;  // 16B store
typedef __attribute__((ext_vector_type(4))) float f32x4;           // MFMA C/D frag

typedef const __attribute__((address_space(1))) void* gptr1_t;
typedef __attribute__((address_space(3))) void* lptr3_t;

#define GLOAD_LDS16(gp, lp) \
  __builtin_amdgcn_global_load_lds((gptr1_t)(gp), (lptr3_t)(lp), 16, 0, 0)

__device__ __forceinline__ uint16_t f2bf(float f) {
  uint32_t u = __builtin_bit_cast(uint32_t, f);
  u += 0x7fffu + ((u >> 16) & 1u);   // RNE
  return (uint16_t)(u >> 16);
}

// ---------------- problem constants ----------------
#define MB   16384      // batch
#define NP   256        // W*H positions
#define KDIM 1024       // NP*EMB
#define NDIM 1024       // OUT

// ---------------- kernel 1: A[b][p*4+e] = bf16(W_embed[x[b][p]][e] + b_embed[e]) ----------
// 2 positions per thread: int2 index read, 16B output store.
__global__ void build_a_kernel(const int* __restrict__ x,
                               const float* __restrict__ We,
                               const float* __restrict__ be,
                               uint16_t* __restrict__ A) {
  const int t = blockIdx.x * 256 + threadIdx.x;   // over MB*NP/2
  const int2 cls = ((const int2*)x)[t];
  const float4 e0 = *(const float4*)(We + (size_t)cls.x * 4);  // 16 KB table, L1-hot
  const float4 e1 = *(const float4*)(We + (size_t)cls.y * 4);
  const float4 bb = *(const float4*)be;
  u16x8 o = { f2bf(e0.x + bb.x), f2bf(e0.y + bb.y), f2bf(e0.z + bb.z), f2bf(e0.w + bb.w),
              f2bf(e1.x + bb.x), f2bf(e1.y + bb.y), f2bf(e1.z + bb.z), f2bf(e1.w + bb.w) };
  *(u16x8*)(A + (size_t)t * 8) = o;               // coalesced 16B stores
}

// ---------------- kernel 2: Bt[n][k] = bf16(W_dense[k][n]) (transpose + cast) ----------------
__global__ void build_bt_kernel(const float* __restrict__ Wd,
                                uint16_t* __restrict__ Bt) {
  __shared__ uint16_t tile[32][33];               // +1 pad: no bank conflicts
  const int k0 = blockIdx.y * 32;
  const int n0 = blockIdx.x * 32;
  const int tx = threadIdx.x;                     // 0..31
  const int ty = threadIdx.y;                     // 0..7
  #pragma unroll
  for (int r = 0; r < 32; r += 8)
    tile[ty + r][tx] = f2bf(Wd[(size_t)(k0 + ty + r) * NDIM + n0 + tx]);
  __syncthreads();
  #pragma unroll
  for (int r = 0; r < 32; r += 8)
    Bt[(size_t)(n0 + ty + r) * KDIM + k0 + tx] = tile[tx][ty + r];
}

// ---------------- kernel 3: bf16 GEMM, C = A @ Bt^T + bias ----------------
// A: M x K bf16 row-major; Bt: N x K bf16 row-major; C: M x N fp32.
// BK=64 staged as TWO independent 128x32 half-tiles: preserves the verified
// BK=32 LDS row-stride (64B) for conflict-free-enough frag reads while
// halving barrier-pair count (16 iters, 32 MFMAs per barrier-pair).
#define BM  128
#define BN  128
#define BKH 32
#define BK  64
#define NK  (KDIM / BK)   // 16

__global__ __launch_bounds__(256) void gemm_bt_kernel(
    const uint16_t* __restrict__ A,
    const uint16_t* __restrict__ Bt,
    const float* __restrict__ bias,
    float* __restrict__ C) {
  __shared__ uint16_t As[2][BM * BKH];   // 2 x 8 KB
  __shared__ uint16_t Bs[2][BN * BKH];   // 2 x 8 KB

  const int tid  = threadIdx.x;
  const int bm   = blockIdx.x;       // 128 m-tiles
  const int bn   = blockIdx.y;       // 8 n-tiles
  const int wave = tid >> 6;
  const int lane = tid & 63;
  const int wr   = wave >> 1;        // 2x2 wave grid, 64x64 per wave
  const int wc   = wave & 1;
  const int lm   = lane & 15;
  const int q    = lane >> 4;

  const int row0 = bm * BM;
  const int col0 = bn * BN;

  // staging: each thread loads 16B per call; lane-contiguous => row-major half-tile
  const int srow = tid >> 2;          // 0..63
  const int scol = (tid & 3) * 8;     // 8 bf16 = 16B

  f32x4 acc[4][4];
  #pragma unroll
  for (int i = 0; i < 4; i++)
    #pragma unroll
    for (int j = 0; j < 4; j++)
      acc[i][j] = (f32x4){0.f, 0.f, 0.f, 0.f};

  for (int kt = 0; kt < NK; ++kt) {
    const int k0 = kt * BK;
    #pragma unroll
    for (int h = 0; h < 2; ++h) {
      GLOAD_LDS16(A  + (size_t)(row0      + srow) * KDIM + k0 + h * BKH + scol, As[h] + tid * 8);
      GLOAD_LDS16(A  + (size_t)(row0 + 64 + srow) * KDIM + k0 + h * BKH + scol, As[h] + 2048 + tid * 8);
      GLOAD_LDS16(Bt + (size_t)(col0      + srow) * KDIM + k0 + h * BKH + scol, Bs[h] + tid * 8);
      GLOAD_LDS16(Bt + (size_t)(col0 + 64 + srow) * KDIM + k0 + h * BKH + scol, Bs[h] + 2048 + tid * 8);
    }
    __syncthreads();

    #pragma unroll
    for (int h = 0; h < 2; ++h) {
      bf16x8 af[4], bfr[4];
      #pragma unroll
      for (int i = 0; i < 4; i++)
        af[i] = *(const bf16x8*)(As[h] + (wr * 64 + i * 16 + lm) * BKH + q * 8);
      #pragma unroll
      for (int j = 0; j < 4; j++)
        bfr[j] = *(const bf16x8*)(Bs[h] + (wc * 64 + j * 16 + lm) * BKH + q * 8);

      #pragma unroll
      for (int i = 0; i < 4; i++)
        #pragma unroll
        for (int j = 0; j < 4; j++)
          acc[i][j] = __builtin_amdgcn_mfma_f32_16x16x32_bf16(af[i], bfr[j], acc[i][j], 0, 0, 0);
    }

    __syncthreads();
  }

  // epilogue: D[row = q*4 + r][col = lm] per 16x16 frag (m89/m91-verified layout)
  float bvals[4];
  #pragma unroll
  for (int j = 0; j < 4; j++)
    bvals[j] = bias[col0 + wc * 64 + j * 16 + lm];

  #pragma unroll
  for (int i = 0; i < 4; i++) {
    const int rbase = row0 + wr * 64 + i * 16 + q * 4;
    #pragma unroll
    for (int j = 0; j < 4; j++) {
      const int col = col0 + wc * 64 + j * 16 + lm;
      #pragma unroll
      for (int r = 0; r < 4; r++)
        C[(size_t)(rbase + r) * NDIM + col] = acc[i][j][r] + bvals[j];
    }
  }
}

// ---------------- fallback (workspace too small): fp32 naive ----------------
__global__ void naive_kernel(const int* __restrict__ x,
                             const float* __restrict__ We,
                             const float* __restrict__ be,
                             const float* __restrict__ Wd,
                             const float* __restrict__ bd,
                             float* __restrict__ out) {
  __shared__ float emb[KDIM];
  const int b = blockIdx.x;
  const int tid = threadIdx.x;
  {
    const int cls = x[(size_t)b * NP + tid];
    const float4 e  = *(const float4*)(We + (size_t)cls * 4);
    const float4 bb = *(const float4*)be;
    emb[tid * 4 + 0] = e.x + bb.x;
    emb[tid * 4 + 1] = e.y + bb.y;
    emb[tid * 4 + 2] = e.z + bb.z;
    emb[tid * 4 + 3] = e.w + bb.w;
  }
  __syncthreads();
  float acc0 = bd[tid], acc1 = bd[tid + 256], acc2 = bd[tid + 512], acc3 = bd[tid + 768];
  for (int k = 0; k < KDIM; ++k) {
    const float a = emb[k];
    const float* w = Wd + (size_t)k * NDIM + tid;
    acc0 += a * w[0];
    acc1 += a * w[256];
    acc2 += a * w[512];
    acc3 += a * w[768];
  }
  float* o = out + (size_t)b * NDIM + tid;
  o[0] = acc0; o[256] = acc1; o[512] = acc2; o[768] = acc3;
}

// ---------------- launch ----------------
extern "C" void kernel_launch(void* const* d_in, const int* in_sizes, int n_in,
                              void* d_out, int out_size, void* d_ws, size_t ws_size,
                              hipStream_t stream) {
  const int*   x  = (const int*)d_in[0];
  const float* We = (const float*)d_in[1];
  const float* be = (const float*)d_in[2];
  const float* Wd = (const float*)d_in[3];
  const float* bd = (const float*)d_in[4];
  float* out = (float*)d_out;

  const size_t needA = (size_t)MB * KDIM * sizeof(uint16_t);    // 33.5 MB
  const size_t needB = (size_t)NDIM * KDIM * sizeof(uint16_t);  // 2 MB

  if (ws_size >= needA + needB) {
    uint16_t* Aw  = (uint16_t*)d_ws;
    uint16_t* Btw = (uint16_t*)((char*)d_ws + needA);
    build_a_kernel<<<MB * NP / 2 / 256, 256, 0, stream>>>(x, We, be, Aw);
    build_bt_kernel<<<dim3(NDIM / 32, KDIM / 32), dim3(32, 8), 0, stream>>>(Wd, Btw);
    gemm_bt_kernel<<<dim3(MB / BM, NDIM / BN), 256, 0, stream>>>(Aw, Btw, bd, out);
  } else {
    naive_kernel<<<MB, 256, 0, stream>>>(x, We, be, Wd, bd, out);
  }
}